// Round 1
// baseline (536.343 us; speedup 1.0000x reference)
//
#include <hip/hip_runtime.h>
#include <stdint.h>

// y[t][o] = sum_i x[t][i] * ((w_pos[o][i]>0) - (w_neg[o][i]>0))
// One bf16 GEMM vs ternary weights (ternary is exact in bf16).
// M=8192, N=4096, K=4096. fp32 out.
// ws: [0,64MiB) x_bf16 ; [64MiB,96MiB) tern_bf16.
//
// GEMM: 256x256 tile, BK=64, 8 waves (2Mx4N), 128 KiB LDS double buffer,
// 8-phase schedule with counted vmcnt(6) (never 0 in main loop), setprio
// around MFMA clusters, bijective XCD block swizzle. (m194-m201 template.)

#define TOKENS 8192
#define DIN    4096
#define DOUT   4096

typedef __bf16  bf16x8  __attribute__((ext_vector_type(8)));
typedef float   floatx4 __attribute__((ext_vector_type(4)));

__device__ __forceinline__ void async_copy16(const void* g, void* l) {
  __builtin_amdgcn_global_load_lds(
      (const __attribute__((address_space(1))) void*)g,
      (__attribute__((address_space(3))) void*)l, 16, 0, 0);
}

__device__ __forceinline__ unsigned short f2bf_rne(float f) {
  union { float f; uint32_t u; } v; v.f = f;
  uint32_t u = v.u;
  u += 0x7fffu + ((u >> 16) & 1u);
  return (unsigned short)(u >> 16);
}

__device__ __forceinline__ unsigned short tern_bits(float p, float n) {
  bool bp = p > 0.0f, bn = n > 0.0f;
  return (unsigned short)(bp == bn ? 0u : (bp ? 0x3f80u : 0xbf80u));
}

// Grid-stride x4: 8192 blocks x 256 thr, 4 float4 per thread.
__global__ __launch_bounds__(256) void cvt_x_kernel(
    const float4* __restrict__ x, ushort4* __restrict__ xb) {
  const uint32_t stride = gridDim.x * blockDim.x;
  uint32_t i = blockIdx.x * blockDim.x + threadIdx.x;
#pragma unroll
  for (int it = 0; it < 4; ++it, i += stride) {
    float4 v = x[i];
    ushort4 o;
    o.x = f2bf_rne(v.x); o.y = f2bf_rne(v.y);
    o.z = f2bf_rne(v.z); o.w = f2bf_rne(v.w);
    xb[i] = o;
  }
}

// 4096 blocks x 256 thr, 4 float4-pairs per thread.
__global__ __launch_bounds__(256) void tern_kernel(
    const float4* __restrict__ wp, const float4* __restrict__ wn,
    ushort4* __restrict__ t) {
  const uint32_t stride = gridDim.x * blockDim.x;
  uint32_t i = blockIdx.x * blockDim.x + threadIdx.x;
#pragma unroll
  for (int it = 0; it < 4; ++it, i += stride) {
    float4 p = wp[i];
    float4 n = wn[i];
    ushort4 o;
    o.x = tern_bits(p.x, n.x);
    o.y = tern_bits(p.y, n.y);
    o.z = tern_bits(p.z, n.z);
    o.w = tern_bits(p.w, n.w);
    t[i] = o;
  }
}

// ---------------------------------------------------------------------------
// GEMM C[M,N] = A[M,K] * B[N,K]^T, bf16 in, fp32 out.
//
// LDS map (per buffer b in {0,1}, base b*65536):
//   A tile:  [+0     ] : khalf 0 = [256 rows][64 B], khalf 1 at +16384
//   B tile:  [+32768 ] : same layout
// Within each 64-B row (4 chunks of 16 B), chunk c stored at slot
// c ^ ((row>>1)&3)  -> every 8 consecutive rows of a fragment column span
// all 8 16B-slots (2-way aliasing max = conflict-free). global_load_lds
// writes LDS linearly; the swizzle is applied on the per-lane GLOBAL source
// address (staging) and on the LDS read address (fragments).
//
// Phase schedule per iteration i (tiles T0=2i in buf0, T1=2i+1 in buf1),
// regions named {A|B}.{k0|k1} (16 KiB each, = 2 global_load_lds/thread):
//   Ph1 (T0,kc0,mh0): reads A[m0-3]+B[all]   stage buf1.A.k1 <- T(2i+1)
//   Ph2 (T0,kc0,mh1): reads A[m4-7]          stage buf0.B.k0 <- T(2i+2)
//   Ph3 (T0,kc1,mh0): reads A[m0-3]+B[all]   stage buf0.A.k0 <- T(2i+2)
//   Ph4 (T0,kc1,mh1): reads A[m4-7]          stage buf0.B.k1 <- T(2i+2)  vmcnt(6)
//   Ph5 (T1,kc0,mh0):                        stage buf0.A.k1 <- T(2i+2)
//   Ph6 (T1,kc0,mh1):                        stage buf1.B.k0 <- T(2i+3)
//   Ph7 (T1,kc1,mh0):                        stage buf1.A.k0 <- T(2i+3)
//   Ph8 (T1,kc1,mh1):                        stage buf1.B.k1 <- T(2i+3)  vmcnt(6)
// WAR: each staged region's last ds_read retired (lgkmcnt(0) pre-MFMA) at
// least one barrier before the stage issues. RAW: vmcnt(6) at Ph4 retires
// through Ph1's stage => T1 complete; at Ph8 through Ph5's => T2 complete.
// ---------------------------------------------------------------------------

#define LDS_BUF   65536u
#define LDS_B_OFF 32768u
#define LDS_KC    16384u

__global__ __launch_bounds__(512, 2) void gemm_bt(
    const unsigned short* __restrict__ A,   // [TOKENS][DIN] bf16
    const unsigned short* __restrict__ B,   // [DOUT][DIN]   bf16 ternary
    float* __restrict__ C)                  // [TOKENS][DOUT] fp32
{
  __shared__ __align__(16) char lds[131072];

  const int tid   = threadIdx.x;
  const int lane  = tid & 63;
  const int wid   = tid >> 6;
  const int waveM = wid >> 2;   // 0..1
  const int waveN = wid & 3;    // 0..3

  // Bijective XCD swizzle: 512 blocks = 8 XCDs x 64 contiguous tiles.
  const uint32_t flat = blockIdx.x;
  const uint32_t swz  = ((flat & 7u) << 6) | (flat >> 3);
  const uint32_t bm = (swz >> 4) * 256u;    // 0..31 -> M
  const uint32_t bn = (swz & 15u) * 256u;   // 0..15 -> N

  // --- staging constants: wave w, load j cover LDS [w*2048 + j*1024 + l*16)
  // of a 16 KiB region; region row = off>>6, slot = (off>>4)&3.
  const uint32_t srow  = (uint32_t)(tid >> 6) * 32u + (uint32_t)((tid & 63) >> 2);
  const uint32_t slot  = (uint32_t)(tid & 3);
  const uint32_t chnk  = slot ^ ((srow >> 1) & 3u);   // pre-swizzled global chunk
  const uint32_t stA   = (bm + srow) * (DIN * 2u) + chnk * 16u;
  const uint32_t stB   = (bn + srow) * (DIN * 2u) + chnk * 16u;
  const uint32_t ldsSt = (uint32_t)(tid >> 6) * 2048u + (uint32_t)(tid & 63) * 16u;
  const char* Ab = (const char*)A;
  const char* Bb = (const char*)B;

  // --- fragment constants
  const int mrow = lane & 15;
  const int q    = lane >> 4;
  const int xs   = (q ^ ((mrow >> 1) & 3)) * 16;
  const uint32_t aFragBase = (uint32_t)waveM * 8192u + (uint32_t)mrow * 64u + (uint32_t)xs;
  const uint32_t bFragBase = LDS_B_OFF + (uint32_t)waveN * 4096u
                           + (uint32_t)mrow * 64u + (uint32_t)xs;

  floatx4 acc[8][4];
#pragma unroll
  for (int m = 0; m < 8; ++m)
#pragma unroll
    for (int n = 0; n < 4; ++n)
      acc[m][n] = (floatx4)0.0f;

  bf16x8 a[4], b[4];

#define STAGE_A(BUF, KH, KB) do {                                          \
    uint32_t g_ = stA + (KB) + (KH) * 64u;                                 \
    uint32_t l_ = (BUF) * LDS_BUF + (KH) * LDS_KC + ldsSt;                 \
    async_copy16(Ab + g_,           lds + l_);                             \
    async_copy16(Ab + g_ + 131072u, lds + l_ + 1024u);                     \
  } while (0)

#define STAGE_B(BUF, KH, KB) do {                                          \
    uint32_t g_ = stB + (KB) + (KH) * 64u;                                 \
    uint32_t l_ = (BUF) * LDS_BUF + LDS_B_OFF + (KH) * LDS_KC + ldsSt;     \
    async_copy16(Bb + g_,           lds + l_);                             \
    async_copy16(Bb + g_ + 131072u, lds + l_ + 1024u);                     \
  } while (0)

#define PHASE(BUF, KC, MH, STAGE_STMT) do {                                \
    if ((MH) == 0) {                                                       \
      _Pragma("unroll")                                                    \
      for (int n_ = 0; n_ < 4; ++n_)                                       \
        b[n_] = *(const bf16x8*)(lds + (BUF) * LDS_BUF + (KC) * LDS_KC     \
                                 + (uint32_t)n_ * 1024u + bFragBase);      \
      _Pragma("unroll")                                                    \
      for (int m_ = 0; m_ < 4; ++m_)                                       \
        a[m_] = *(const bf16x8*)(lds + (BUF) * LDS_BUF + (KC) * LDS_KC     \
                                 + (uint32_t)m_ * 1024u + aFragBase);      \
    } else {                                                               \
      _Pragma("unroll")                                                    \
      for (int m_ = 0; m_ < 4; ++m_)                                       \
        a[m_] = *(const bf16x8*)(lds + (BUF) * LDS_BUF + (KC) * LDS_KC     \
                                 + (uint32_t)(m_ + 4) * 1024u + aFragBase);\
    }                                                                      \
    STAGE_STMT;                                                            \
    __builtin_amdgcn_s_barrier();                                          \
    asm volatile("s_waitcnt lgkmcnt(0)" ::: "memory");                     \
    __builtin_amdgcn_sched_barrier(0);                                     \
    __builtin_amdgcn_s_setprio(1);                                         \
    _Pragma("unroll")                                                      \
    for (int m_ = 0; m_ < 4; ++m_)                                         \
      _Pragma("unroll")                                                    \
      for (int n_ = 0; n_ < 4; ++n_)                                       \
        acc[(MH) * 4 + m_][n_] = __builtin_amdgcn_mfma_f32_16x16x32_bf16(  \
            a[m_], b[n_], acc[(MH) * 4 + m_][n_], 0, 0, 0);                \
    __builtin_amdgcn_s_setprio(0);                                         \
  } while (0)

#define VM6 asm volatile("s_waitcnt vmcnt(6)" ::: "memory")
#define BAR __builtin_amdgcn_s_barrier()

  // Prologue: all of T0, then T1.{B.k0, A.k0, B.k1} (T1.A.k1 comes at Ph1).
  STAGE_B(0, 0, 0u);   STAGE_A(0, 0, 0u);
  STAGE_B(0, 1, 0u);   STAGE_A(0, 1, 0u);
  STAGE_B(1, 0, 128u); STAGE_A(1, 0, 128u);
  STAGE_B(1, 1, 128u);
  VM6;   // oldest 8 (all of T0) retired; T1's 6 may stay in flight
  BAR;

#pragma unroll 1
  for (int i = 0; i < 32; ++i) {
    const uint32_t kb1 = (uint32_t)(2 * i + 1) * 128u;          // <= 8064
    const uint32_t kb2 = (uint32_t)((2 * i + 2) & 63) * 128u;   // wraps: garbage-stage, never read
    const uint32_t kb3 = (uint32_t)((2 * i + 3) & 63) * 128u;

    PHASE(0, 0, 0, STAGE_A(1, 1, kb1));        BAR;   // Ph1
    PHASE(0, 0, 1, STAGE_B(0, 0, kb2));        BAR;   // Ph2
    PHASE(0, 1, 0, STAGE_A(0, 0, kb2));        BAR;   // Ph3
    PHASE(0, 1, 1, STAGE_B(0, 1, kb2));  VM6;  BAR;   // Ph4: T1 fully landed
    PHASE(1, 0, 0, STAGE_A(0, 1, kb2));        BAR;   // Ph5
    PHASE(1, 0, 1, STAGE_B(1, 0, kb3));        BAR;   // Ph6
    PHASE(1, 1, 0, STAGE_A(1, 0, kb3));        BAR;   // Ph7
    PHASE(1, 1, 1, STAGE_B(1, 1, kb3));  VM6;  BAR;   // Ph8: T2 fully landed
  }

  // C/D layout: col = lane&15, row = (lane>>4)*4 + reg.
  const int col0 = (int)bn + waveN * 64 + (lane & 15);
  const int row0 = (int)bm + waveM * 128 + (lane >> 4) * 4;
  float* Cp = C + (size_t)row0 * DOUT + col0;
#pragma unroll
  for (int m = 0; m < 8; ++m)
#pragma unroll
    for (int n = 0; n < 4; ++n)
#pragma unroll
      for (int r = 0; r < 4; ++r)
        Cp[(size_t)(m * 16 + r) * DOUT + n * 16] = acc[m][n][r];

#undef STAGE_A
#undef STAGE_B
#undef PHASE
#undef VM6
#undef BAR
}

extern "C" void kernel_launch(void* const* d_in, const int* in_sizes, int n_in,
                              void* d_out, int out_size, void* d_ws, size_t ws_size,
                              hipStream_t stream) {
  const float* x  = (const float*)d_in[0];   // [8192, 4096] fp32
  const float* wp = (const float*)d_in[1];   // [4096, 4096] fp32
  const float* wn = (const float*)d_in[2];   // [4096, 4096] fp32
  float* out = (float*)d_out;                // [8192, 4096] fp32

  unsigned short* xb   = (unsigned short*)d_ws;
  unsigned short* tern = xb + (size_t)TOKENS * DIN;

  // TOKENS*DIN/4 float4s, 4 per thread -> 8192 blocks
  cvt_x_kernel<<<TOKENS * DIN / 4 / 4 / 256, 256, 0, stream>>>(
      (const float4*)x, (ushort4*)xb);
  // DOUT*DIN/4 float4s, 4 per thread -> 4096 blocks
  tern_kernel<<<DOUT * DIN / 4 / 4 / 256, 256, 0, stream>>>(
      (const float4*)wp, (const float4*)wn, (ushort4*)tern);

  // 512 blocks (1D, XCD-swizzled in-kernel) x 512 threads.
  gemm_bt<<<TOKENS / 256 * (DOUT / 256), 512, 0, stream>>>(xb, tern, out);
}